// Round 4
// baseline (412.056 us; speedup 1.0000x reference)
//
#include <hip/hip_runtime.h>
#include <math.h>

#define NTOK 2048      // B*S
#define DDIM 1024
#define HDIM 2048
#define NE 8
#define EPS_RMS 1e-5f
#define EPS_TOPK 1e-10f

#define KSPLIT 4
#define KCH (HDIM / KSPLIT)   // 512

typedef short short8 __attribute__((ext_vector_type(8)));
typedef float f32x4  __attribute__((ext_vector_type(4)));

__device__ __forceinline__ unsigned short f2bf(float a) {
    unsigned ua = __builtin_bit_cast(unsigned, a);
    return (unsigned short)((ua + 0x7fffu + ((ua >> 16) & 1u)) >> 16);
}

// async global->LDS, 16B per lane; lds base must be wave-uniform (lane i lands at base + i*16)
__device__ __forceinline__ void gl2lds16(const unsigned short* g, unsigned short* l) {
    __builtin_amdgcn_global_load_lds(
        (const __attribute__((address_space(1))) unsigned int*)g,
        (__attribute__((address_space(3))) unsigned int*)l,
        16, 0, 0);
}

// ---------------- Kernel 0: weight convert+transpose fp32 -> bf16 B^T layouts ----------------
// wcatT[e][n][d], n = (h>>5)*64 + which*32 + (h&31)  (which: 0=w1, 1=w2)  -> [8][4096][1024]
// w3T[e][d][h] -> [8][1024][2048]
// grid (32, 32, NE*3), block 256
__global__ __launch_bounds__(256) void k_wconv(
        const float* __restrict__ w1, const float* __restrict__ w2,
        const float* __restrict__ w3,
        unsigned short* __restrict__ wcatT, unsigned short* __restrict__ w3T) {
    int z = blockIdx.z;
    int e = z / 3, mat = z % 3;
    int R, C;
    const float* src;
    if (mat < 2) { R = DDIM; C = HDIM; src = (mat == 0 ? w1 : w2) + (size_t)e * DDIM * HDIM; }
    else         { R = HDIM; C = DDIM; src = w3 + (size_t)e * HDIM * DDIM; }
    int c0 = blockIdx.x * 64, r0 = blockIdx.y * 64;
    if (c0 >= C || r0 >= R) return;

    __shared__ float tile[64][65];
    int tid = threadIdx.x;
    int tr = tid >> 6, tc = tid & 63;

    #pragma unroll
    for (int i = 0; i < 16; i++)
        tile[tr + 4 * i][tc] = src[(size_t)(r0 + tr + 4 * i) * C + c0 + tc];
    __syncthreads();

    #pragma unroll
    for (int i = 0; i < 16; i++) {
        int cl = tr + 4 * i;            // src col within tile -> dst row
        int rl = tc;                    // src row within tile -> dst col
        unsigned short v = f2bf(tile[rl][cl]);
        if (mat < 2) {
            int h = c0 + cl;
            int n = ((h >> 5) << 6) + mat * 32 + (h & 31);
            wcatT[((size_t)e * 4096 + n) * 1024 + r0 + rl] = v;
        } else {
            int d = c0 + cl;
            w3T[((size_t)e * 1024 + d) * 2048 + r0 + rl] = v;
        }
    }
}

// ---------------- Kernel 1: RMSNorm + router, one wave per token ----------------
__global__ __launch_bounds__(256) void k_norm_router(
        const float* __restrict__ x,
        const float* __restrict__ g,
        const float* __restrict__ gate_w,
        unsigned short* __restrict__ x_norm,
        int* __restrict__ counts,
        int* __restrict__ slot_token,
        float* __restrict__ slot_prob) {
    int lane = threadIdx.x & 63;
    int token = blockIdx.x * 4 + (threadIdx.x >> 6);
    const float* xrow = x + (size_t)token * DDIM;

    float v[16];
    float ss = 0.f;
    #pragma unroll
    for (int i = 0; i < 16; i++) {
        float t = xrow[lane + i * 64];
        v[i] = t;
        ss += t * t;
    }
    #pragma unroll
    for (int o = 32; o > 0; o >>= 1) ss += __shfl_down(ss, o, 64);
    float scale = rsqrtf(__shfl(ss, 0, 64) * (1.f / (float)DDIM) + EPS_RMS);

    float part[NE];
    #pragma unroll
    for (int e = 0; e < NE; e++) part[e] = 0.f;
    #pragma unroll
    for (int i = 0; i < 16; i++) {
        int d = lane + i * 64;
        float xn = v[i] * scale * g[d];
        x_norm[(size_t)token * DDIM + d] = f2bf(xn);
        #pragma unroll
        for (int e = 0; e < NE; e++) part[e] += xn * gate_w[e * DDIM + d];
    }
    #pragma unroll
    for (int e = 0; e < NE; e++) {
        #pragma unroll
        for (int o = 32; o > 0; o >>= 1) part[e] += __shfl_down(part[e], o, 64);
    }

    if (lane == 0) {
        float mx = part[0];
        #pragma unroll
        for (int e = 1; e < NE; e++) mx = fmaxf(mx, part[e]);
        float p[NE];
        float Z = 0.f;
        #pragma unroll
        for (int e = 0; e < NE; e++) { p[e] = __expf(part[e] - mx); Z += p[e]; }
        float rz = 1.f / Z;
        #pragma unroll
        for (int e = 0; e < NE; e++) p[e] *= rz;
        int i1 = 0;
        #pragma unroll
        for (int e = 1; e < NE; e++) if (p[e] > p[i1]) i1 = e;
        int i2 = -1;
        #pragma unroll
        for (int e = 0; e < NE; e++) {
            if (e == i1) continue;
            if (i2 < 0 || p[e] > p[i2]) i2 = e;
        }
        float denom = p[i1] + p[i2] + EPS_TOPK;
        int pos1 = atomicAdd(&counts[i1], 1);
        slot_token[i1 * NTOK + pos1] = token;
        slot_prob[i1 * NTOK + pos1] = p[i1] / denom;
        int pos2 = atomicAdd(&counts[i2], 1);
        slot_token[i2 * NTOK + pos2] = token;
        slot_prob[i2 * NTOK + pos2] = p[i2] / denom;
    }
}

// ---------------- Kernel 2: gathered GEMM X @ [W1|W2] + fused SiLU -> hidden bf16 ----------------
// grid: (4096/128=32, NTOK/128=16, NE), block 256 (4 waves, 2x2, each 64x64)
__global__ __launch_bounds__(256) void k_ffn_h(
        const unsigned short* __restrict__ x_norm,  // bf16 [NTOK][1024]
        const unsigned short* __restrict__ wcatT,   // bf16 [E][4096][1024]
        const int* __restrict__ counts,
        const int* __restrict__ slot_token,
        unsigned short* __restrict__ hidden) {      // bf16 [4096 slots][2048]
    int e = blockIdx.z;
    int cnt = counts[e];
    int m0 = blockIdx.y * 128;
    if (m0 >= cnt) return;
    int n0 = blockIdx.x * 128;
    int off = 0;
    for (int i = 0; i < e; i++) off += counts[i];

    int tid = threadIdx.x, lane = tid & 63, wv = tid >> 6;
    int l15 = lane & 15, q4 = lane >> 4;
    int wy = wv >> 1, wx = wv & 1;

    __shared__ unsigned short Ash[128 * 32];   // 8 KB, row stride 64 B (no pad: global_load_lds)
    __shared__ unsigned short Bsh[128 * 32];   // 8 KB
    __shared__ int tok[128];

    if (tid < 128) {
        int idx = m0 + tid;
        tok[tid] = (idx < cnt) ? slot_token[e * NTOK + idx] : slot_token[e * NTOK];
    }
    __syncthreads();

    // staging addressing: wave wv, instr i: row = wv*32 + i*16 + (lane>>2), ksub = (lane&3)*8
    int arow = wv * 32 + (lane >> 2);
    int t0 = tok[arow];
    int t1 = tok[arow + 16];
    const unsigned short* ag0 = x_norm + (size_t)t0 * DDIM + (lane & 3) * 8;
    const unsigned short* ag1 = x_norm + (size_t)t1 * DDIM + (lane & 3) * 8;
    const unsigned short* bg0 = wcatT + ((size_t)e * 4096 + n0 + arow) * 1024 + (lane & 3) * 8;
    const unsigned short* bg1 = bg0 + (size_t)16 * 1024;
    unsigned short* alds = &Ash[wv * 1024];
    unsigned short* blds = &Bsh[wv * 1024];

    f32x4 acc[4][4];
    #pragma unroll
    for (int i = 0; i < 4; i++)
        #pragma unroll
        for (int j = 0; j < 4; j++) acc[i][j] = (f32x4){0.f, 0.f, 0.f, 0.f};

    for (int d0 = 0; d0 < DDIM; d0 += 32) {
        __syncthreads();
        gl2lds16(ag0 + d0, alds);
        gl2lds16(ag1 + d0, alds + 512);
        gl2lds16(bg0 + d0, blds);
        gl2lds16(bg1 + d0, blds + 512);
        __syncthreads();

        short8 af[4], bf[4];
        #pragma unroll
        for (int i = 0; i < 4; i++) {
            af[i] = *(const short8*)&Ash[(wy * 64 + i * 16 + l15) * 32 + q4 * 8];
            bf[i] = *(const short8*)&Bsh[(wx * 64 + i * 16 + l15) * 32 + q4 * 8];
        }
        #pragma unroll
        for (int rf = 0; rf < 4; rf++)
            #pragma unroll
            for (int cf = 0; cf < 4; cf++)
                acc[rf][cf] = __builtin_amdgcn_mfma_f32_16x16x32_bf16(af[rf], bf[cf], acc[rf][cf], 0, 0, 0);
    }

    // epilogue: within this wave, cf 0,1 = w1 cols, cf 2,3 = w2 cols for the same h
    // h = n0/2 + wx*32 + hg*16 + l15 ; C layout col=l15, row=q4*4+r
    #pragma unroll
    for (int rf = 0; rf < 4; rf++) {
        int rowl = wy * 64 + rf * 16 + q4 * 4;
        #pragma unroll
        for (int hg = 0; hg < 2; hg++) {
            int h = (n0 >> 1) + wx * 32 + hg * 16 + l15;
            #pragma unroll
            for (int r = 0; r < 4; r++) {
                int rr = rowl + r;
                if (m0 + rr < cnt) {
                    float a = acc[rf][hg][r];
                    float b = acc[rf][hg + 2][r];
                    float hv = (a / (1.f + __expf(-a))) * b;
                    hidden[(size_t)(off + m0 + rr) * HDIM + h] = f2bf(hv);
                }
            }
        }
    }
}

// ---------------- Kernel 3: GEMM hidden @ w3T^T, K-split, weighted atomic scatter ----------------
// grid: (1024/128=8, NTOK/128=16, NE*KSPLIT), block 256
__global__ __launch_bounds__(256) void k_ffn_out(
        const unsigned short* __restrict__ hidden,  // bf16 [4096][2048]
        const unsigned short* __restrict__ w3T,     // bf16 [E][1024][2048]
        const int* __restrict__ counts,
        const int* __restrict__ slot_token,
        const float* __restrict__ slot_prob,
        float* __restrict__ out) {
    int e = blockIdx.z >> 2;
    int ks = blockIdx.z & 3;
    int cnt = counts[e];
    int m0 = blockIdx.y * 128;
    if (m0 >= cnt) return;
    int d0 = blockIdx.x * 128;
    int off = 0;
    for (int i = 0; i < e; i++) off += counts[i];
    int hb = ks * KCH;

    int tid = threadIdx.x, lane = tid & 63, wv = tid >> 6;
    int l15 = lane & 15, q4 = lane >> 4;
    int wy = wv >> 1, wx = wv & 1;

    __shared__ unsigned short Ash[128 * 32];
    __shared__ unsigned short Bsh[128 * 32];
    __shared__ int tokL[128];
    __shared__ float prbL[128];

    if (tid < 128) {
        int idx = m0 + tid;
        tokL[tid] = (idx < cnt) ? slot_token[e * NTOK + idx] : 0;
        prbL[tid] = (idx < cnt) ? slot_prob[e * NTOK + idx] : 0.f;
    }
    __syncthreads();

    int arow = wv * 32 + (lane >> 2);
    int s0 = off + ((m0 + arow < cnt) ? m0 + arow : 0);
    int s1 = off + ((m0 + arow + 16 < cnt) ? m0 + arow + 16 : 0);
    const unsigned short* ag0 = hidden + (size_t)s0 * HDIM + hb + (lane & 3) * 8;
    const unsigned short* ag1 = hidden + (size_t)s1 * HDIM + hb + (lane & 3) * 8;
    const unsigned short* bg0 = w3T + ((size_t)e * 1024 + d0 + arow) * 2048 + hb + (lane & 3) * 8;
    const unsigned short* bg1 = bg0 + (size_t)16 * 2048;
    unsigned short* alds = &Ash[wv * 1024];
    unsigned short* blds = &Bsh[wv * 1024];

    f32x4 acc[4][4];
    #pragma unroll
    for (int i = 0; i < 4; i++)
        #pragma unroll
        for (int j = 0; j < 4; j++) acc[i][j] = (f32x4){0.f, 0.f, 0.f, 0.f};

    for (int h0 = 0; h0 < KCH; h0 += 32) {
        __syncthreads();
        gl2lds16(ag0 + h0, alds);
        gl2lds16(ag1 + h0, alds + 512);
        gl2lds16(bg0 + h0, blds);
        gl2lds16(bg1 + h0, blds + 512);
        __syncthreads();

        short8 af[4], bf[4];
        #pragma unroll
        for (int i = 0; i < 4; i++) {
            af[i] = *(const short8*)&Ash[(wy * 64 + i * 16 + l15) * 32 + q4 * 8];
            bf[i] = *(const short8*)&Bsh[(wx * 64 + i * 16 + l15) * 32 + q4 * 8];
        }
        #pragma unroll
        for (int rf = 0; rf < 4; rf++)
            #pragma unroll
            for (int cf = 0; cf < 4; cf++)
                acc[rf][cf] = __builtin_amdgcn_mfma_f32_16x16x32_bf16(af[rf], bf[cf], acc[rf][cf], 0, 0, 0);
    }

    #pragma unroll
    for (int rf = 0; rf < 4; rf++) {
        int rowl = wy * 64 + rf * 16 + q4 * 4;
        #pragma unroll
        for (int cf = 0; cf < 4; cf++) {
            int col = d0 + wx * 64 + cf * 16 + l15;
            #pragma unroll
            for (int r = 0; r < 4; r++) {
                int rr = rowl + r;
                if (m0 + rr < cnt) {
                    atomicAdd(&out[(size_t)tokL[rr] * DDIM + col], acc[rf][cf][r] * prbL[rr]);
                }
            }
        }
    }
}

// ---------------- launch ----------------
extern "C" void kernel_launch(void* const* d_in, const int* in_sizes, int n_in,
                              void* d_out, int out_size, void* d_ws, size_t ws_size,
                              hipStream_t stream) {
    const float* x      = (const float*)d_in[0];
    const float* g      = (const float*)d_in[1];
    const float* gate_w = (const float*)d_in[2];
    const float* w1     = (const float*)d_in[3];
    const float* w2     = (const float*)d_in[4];
    const float* w3     = (const float*)d_in[5];
    float* out = (float*)d_out;

    char* ws = (char*)d_ws;
    int*   counts     = (int*)ws;                 ws += 256;
    int*   slot_token = (int*)ws;                 ws += NE * NTOK * 4;
    float* slot_prob  = (float*)ws;               ws += NE * NTOK * 4;
    unsigned short* x_norm = (unsigned short*)ws; ws += (size_t)NTOK * DDIM * 2;           // 4 MB
    unsigned short* hidden = (unsigned short*)ws; ws += (size_t)NTOK * 2 * HDIM * 2;       // 16 MB
    unsigned short* wcatT  = (unsigned short*)ws; ws += (size_t)NE * 4096 * 1024 * 2;      // 64 MB
    unsigned short* w3T    = (unsigned short*)ws; ws += (size_t)NE * 1024 * 2048 * 2;      // 32 MB

    hipMemsetAsync(counts, 0, 256, stream);
    hipMemsetAsync(out, 0, (size_t)NTOK * DDIM * sizeof(float), stream);

    dim3 grid_c(32, 32, NE * 3);
    k_wconv<<<grid_c, 256, 0, stream>>>(w1, w2, w3, wcatT, w3T);

    k_norm_router<<<NTOK / 4, 256, 0, stream>>>(x, g, gate_w, x_norm, counts, slot_token, slot_prob);

    dim3 grid_h(4096 / 128, NTOK / 128, NE);
    k_ffn_h<<<grid_h, 256, 0, stream>>>(x_norm, wcatT, counts, slot_token, hidden);

    dim3 grid_o(1024 / 128, NTOK / 128, NE * KSPLIT);
    k_ffn_out<<<grid_o, 256, 0, stream>>>(hidden, w3T, counts, slot_token, slot_prob, out);
}

// Round 5
// 377.956 us; speedup vs baseline: 1.0902x; 1.0902x over previous
//
#include <hip/hip_runtime.h>
#include <math.h>

#define NTOK 2048      // B*S
#define DDIM 1024
#define HDIM 2048
#define NE 8
#define EPS_RMS 1e-5f
#define EPS_TOPK 1e-10f

#define KSPLIT 2
#define KCH (HDIM / KSPLIT)   // 1024

typedef short short8 __attribute__((ext_vector_type(8)));
typedef float f32x4  __attribute__((ext_vector_type(4)));

__device__ __forceinline__ unsigned pack2bf(float a, float b) {
    unsigned ua = __builtin_bit_cast(unsigned, a);
    unsigned ub = __builtin_bit_cast(unsigned, b);
    ua = (ua + 0x7fffu + ((ua >> 16) & 1u)) >> 16;
    ub = (ub + 0x7fffu + ((ub >> 16) & 1u)) & 0xffff0000u;
    return ua | ub;
}
__device__ __forceinline__ unsigned short f2bf(float a) {
    unsigned ua = __builtin_bit_cast(unsigned, a);
    return (unsigned short)((ua + 0x7fffu + ((ua >> 16) & 1u)) >> 16);
}

// async global->LDS, 16B per lane; lds base wave-uniform (lane i -> base + i*16)
__device__ __forceinline__ void gl2lds16(const unsigned short* g, unsigned short* l) {
    __builtin_amdgcn_global_load_lds(
        (const __attribute__((address_space(1))) unsigned int*)g,
        (__attribute__((address_space(3))) unsigned int*)l,
        16, 0, 0);
}

// ---------------- Kernel 0: fused weight convert/transpose + RMSNorm/router ----------------
// grid (32, 32, 25), block 256.
// z<24: wconv plane (e = z/3, mat = z%3).  z==24: router plane (rid = y*32+x < 512).
__global__ __launch_bounds__(256) void k_prep(
        const float* __restrict__ w1, const float* __restrict__ w2,
        const float* __restrict__ w3,
        unsigned short* __restrict__ wcatT,   // [E][4096][1024] bf16, n=(h>>5)*64+mat*32+(h&31)
        unsigned short* __restrict__ w3T,     // [E][1024][2048] bf16
        const float* __restrict__ x,
        const float* __restrict__ g,
        const float* __restrict__ gate_w,
        unsigned short* __restrict__ x_norm,
        int* __restrict__ counts,
        int* __restrict__ slot_token,
        float* __restrict__ slot_prob,
        int* __restrict__ tslot) {
    int z = blockIdx.z;
    int tid = threadIdx.x;

    if (z < 24) {
        // ---- weight convert + transpose ----
        int e = z / 3, mat = z % 3;
        int R = (mat < 2) ? DDIM : HDIM;
        int C = (mat < 2) ? HDIM : DDIM;
        const float* src = (mat == 0 ? w1 : (mat == 1 ? w2 : w3)) + (size_t)e * DDIM * HDIM;
        int c0 = blockIdx.x * 64, r0 = blockIdx.y * 64;
        if (c0 >= C || r0 >= R) return;

        __shared__ float tile[64][65];
        #pragma unroll
        for (int pass = 0; pass < 4; pass++) {
            int r = pass * 16 + (tid >> 4);
            int c = (tid & 15) * 4;
            *(float4*)&tile[r][c] = *(const float4*)&src[(size_t)(r0 + r) * C + c0 + c];
        }
        __syncthreads();

        #pragma unroll
        for (int pass = 0; pass < 2; pass++) {
            int cl = pass * 32 + (tid >> 3);   // src col -> dst row
            int j  = (tid & 7) * 8;            // src row offset -> dst col offset
            float f[8];
            #pragma unroll
            for (int jj = 0; jj < 8; jj++) f[jj] = tile[j + jj][cl];
            uint4 pb;
            pb.x = pack2bf(f[0], f[1]); pb.y = pack2bf(f[2], f[3]);
            pb.z = pack2bf(f[4], f[5]); pb.w = pack2bf(f[6], f[7]);
            unsigned short* dst;
            if (mat < 2) {
                int h = c0 + cl;
                int n = ((h >> 5) << 6) + mat * 32 + (h & 31);
                dst = wcatT + ((size_t)e * 4096 + n) * 1024 + r0 + j;
            } else {
                int d = c0 + cl;
                dst = w3T + ((size_t)e * 1024 + d) * 2048 + r0 + j;
            }
            *(uint4*)dst = pb;
        }
        return;
    }

    // ---- router plane ----
    int rid = blockIdx.y * 32 + blockIdx.x;
    if (rid >= NTOK / 4) return;
    int lane = tid & 63;
    int token = rid * 4 + (tid >> 6);
    const float* xrow = x + (size_t)token * DDIM;

    float v[16];
    float ss = 0.f;
    #pragma unroll
    for (int i = 0; i < 16; i++) {
        float t = xrow[lane + i * 64];
        v[i] = t;
        ss += t * t;
    }
    #pragma unroll
    for (int o = 32; o > 0; o >>= 1) ss += __shfl_down(ss, o, 64);
    float scale = rsqrtf(__shfl(ss, 0, 64) * (1.f / (float)DDIM) + EPS_RMS);

    float part[NE];
    #pragma unroll
    for (int e = 0; e < NE; e++) part[e] = 0.f;
    #pragma unroll
    for (int i = 0; i < 16; i++) {
        int d = lane + i * 64;
        float xn = v[i] * scale * g[d];
        x_norm[(size_t)token * DDIM + d] = f2bf(xn);
        #pragma unroll
        for (int e = 0; e < NE; e++) part[e] += xn * gate_w[e * DDIM + d];
    }
    #pragma unroll
    for (int e = 0; e < NE; e++) {
        #pragma unroll
        for (int o = 32; o > 0; o >>= 1) part[e] += __shfl_down(part[e], o, 64);
    }

    if (lane == 0) {
        float mx = part[0];
        #pragma unroll
        for (int e = 1; e < NE; e++) mx = fmaxf(mx, part[e]);
        float p[NE];
        float Z = 0.f;
        #pragma unroll
        for (int e = 0; e < NE; e++) { p[e] = __expf(part[e] - mx); Z += p[e]; }
        float rz = 1.f / Z;
        #pragma unroll
        for (int e = 0; e < NE; e++) p[e] *= rz;
        int i1 = 0;
        #pragma unroll
        for (int e = 1; e < NE; e++) if (p[e] > p[i1]) i1 = e;
        int i2 = -1;
        #pragma unroll
        for (int e = 0; e < NE; e++) {
            if (e == i1) continue;
            if (i2 < 0 || p[e] > p[i2]) i2 = e;
        }
        float denom = p[i1] + p[i2] + EPS_TOPK;
        int pos1 = atomicAdd(&counts[i1], 1);
        slot_token[i1 * NTOK + pos1] = token;
        slot_prob[i1 * NTOK + pos1] = p[i1] / denom;
        tslot[token * 2 + 0] = i1 * NTOK + pos1;
        int pos2 = atomicAdd(&counts[i2], 1);
        slot_token[i2 * NTOK + pos2] = token;
        slot_prob[i2 * NTOK + pos2] = p[i2] / denom;
        tslot[token * 2 + 1] = i2 * NTOK + pos2;
    }
}

// ---------------- Kernel 2: gathered GEMM X @ [W1|W2] + fused SiLU -> hidden bf16 ----------------
// grid: (32, 16, NE), block 256 (4 waves, 2x2, each 64x64)
__global__ __launch_bounds__(256) void k_ffn_h(
        const unsigned short* __restrict__ x_norm,  // bf16 [NTOK][1024]
        const unsigned short* __restrict__ wcatT,   // bf16 [E][4096][1024]
        const int* __restrict__ counts,
        const int* __restrict__ slot_token,
        unsigned short* __restrict__ hidden) {      // bf16 [4096 slots][2048]
    int e = blockIdx.z;
    int cnt = counts[e];
    int m0 = blockIdx.y * 128;
    if (m0 >= cnt) return;
    int n0 = blockIdx.x * 128;
    int off = 0;
    for (int i = 0; i < e; i++) off += counts[i];

    int tid = threadIdx.x, lane = tid & 63, wv = tid >> 6;
    int l15 = lane & 15, q4 = lane >> 4;
    int wy = wv >> 1, wx = wv & 1;

    __shared__ unsigned short Ash[128 * 32];
    __shared__ unsigned short Bsh[128 * 32];
    __shared__ int tok[128];

    if (tid < 128) {
        int idx = m0 + tid;
        tok[tid] = (idx < cnt) ? slot_token[e * NTOK + idx] : slot_token[e * NTOK];
    }
    __syncthreads();

    int arow = wv * 32 + (lane >> 2);
    int t0 = tok[arow];
    int t1 = tok[arow + 16];
    const unsigned short* ag0 = x_norm + (size_t)t0 * DDIM + (lane & 3) * 8;
    const unsigned short* ag1 = x_norm + (size_t)t1 * DDIM + (lane & 3) * 8;
    const unsigned short* bg0 = wcatT + ((size_t)e * 4096 + n0 + arow) * 1024 + (lane & 3) * 8;
    const unsigned short* bg1 = bg0 + (size_t)16 * 1024;
    unsigned short* alds = &Ash[wv * 1024];
    unsigned short* blds = &Bsh[wv * 1024];

    f32x4 acc[4][4];
    #pragma unroll
    for (int i = 0; i < 4; i++)
        #pragma unroll
        for (int j = 0; j < 4; j++) acc[i][j] = (f32x4){0.f, 0.f, 0.f, 0.f};

    for (int d0 = 0; d0 < DDIM; d0 += 32) {
        __syncthreads();
        gl2lds16(ag0 + d0, alds);
        gl2lds16(ag1 + d0, alds + 512);
        gl2lds16(bg0 + d0, blds);
        gl2lds16(bg1 + d0, blds + 512);
        __syncthreads();

        short8 af[4], bf[4];
        #pragma unroll
        for (int i = 0; i < 4; i++) {
            af[i] = *(const short8*)&Ash[(wy * 64 + i * 16 + l15) * 32 + q4 * 8];
            bf[i] = *(const short8*)&Bsh[(wx * 64 + i * 16 + l15) * 32 + q4 * 8];
        }
        #pragma unroll
        for (int rf = 0; rf < 4; rf++)
            #pragma unroll
            for (int cf = 0; cf < 4; cf++)
                acc[rf][cf] = __builtin_amdgcn_mfma_f32_16x16x32_bf16(af[rf], bf[cf], acc[rf][cf], 0, 0, 0);
    }

    // epilogue: cf 0,1 = w1 cols, cf 2,3 = w2 cols for the same h
    #pragma unroll
    for (int rf = 0; rf < 4; rf++) {
        int rowl = wy * 64 + rf * 16 + q4 * 4;
        #pragma unroll
        for (int hg = 0; hg < 2; hg++) {
            int h = (n0 >> 1) + wx * 32 + hg * 16 + l15;
            #pragma unroll
            for (int r = 0; r < 4; r++) {
                int rr = rowl + r;
                if (m0 + rr < cnt) {
                    float a = acc[rf][hg][r];
                    float b = acc[rf][hg + 2][r];
                    float hv = (a / (1.f + __expf(-a))) * b;
                    hidden[(size_t)(off + m0 + rr) * HDIM + h] = f2bf(hv);
                }
            }
        }
    }
}

// ---------------- Kernel 3: GEMM hidden @ w3T^T, K-split, plain partial stores ----------------
// grid: (8, 16, NE*KSPLIT), block 256
__global__ __launch_bounds__(256) void k_ffn_out(
        const unsigned short* __restrict__ hidden,  // bf16 [4096][2048]
        const unsigned short* __restrict__ w3T,     // bf16 [E][1024][2048]
        const int* __restrict__ counts,
        float* __restrict__ yp) {                   // [KSPLIT][4096][1024] f32 partials
    int e = blockIdx.z >> 1;
    int ks = blockIdx.z & 1;
    int cnt = counts[e];
    int m0 = blockIdx.y * 128;
    if (m0 >= cnt) return;
    int d0 = blockIdx.x * 128;
    int off = 0;
    for (int i = 0; i < e; i++) off += counts[i];
    int hb = ks * KCH;

    int tid = threadIdx.x, lane = tid & 63, wv = tid >> 6;
    int l15 = lane & 15, q4 = lane >> 4;
    int wy = wv >> 1, wx = wv & 1;

    __shared__ unsigned short Ash[128 * 32];
    __shared__ unsigned short Bsh[128 * 32];

    int arow = wv * 32 + (lane >> 2);
    int s0 = off + ((m0 + arow < cnt) ? m0 + arow : 0);
    int s1 = off + ((m0 + arow + 16 < cnt) ? m0 + arow + 16 : 0);
    const unsigned short* ag0 = hidden + (size_t)s0 * HDIM + hb + (lane & 3) * 8;
    const unsigned short* ag1 = hidden + (size_t)s1 * HDIM + hb + (lane & 3) * 8;
    const unsigned short* bg0 = w3T + ((size_t)e * 1024 + d0 + arow) * 2048 + hb + (lane & 3) * 8;
    const unsigned short* bg1 = bg0 + (size_t)16 * 2048;
    unsigned short* alds = &Ash[wv * 1024];
    unsigned short* blds = &Bsh[wv * 1024];

    f32x4 acc[4][4];
    #pragma unroll
    for (int i = 0; i < 4; i++)
        #pragma unroll
        for (int j = 0; j < 4; j++) acc[i][j] = (f32x4){0.f, 0.f, 0.f, 0.f};

    for (int h0 = 0; h0 < KCH; h0 += 32) {
        __syncthreads();
        gl2lds16(ag0 + h0, alds);
        gl2lds16(ag1 + h0, alds + 512);
        gl2lds16(bg0 + h0, blds);
        gl2lds16(bg1 + h0, blds + 512);
        __syncthreads();

        short8 af[4], bf[4];
        #pragma unroll
        for (int i = 0; i < 4; i++) {
            af[i] = *(const short8*)&Ash[(wy * 64 + i * 16 + l15) * 32 + q4 * 8];
            bf[i] = *(const short8*)&Bsh[(wx * 64 + i * 16 + l15) * 32 + q4 * 8];
        }
        #pragma unroll
        for (int rf = 0; rf < 4; rf++)
            #pragma unroll
            for (int cf = 0; cf < 4; cf++)
                acc[rf][cf] = __builtin_amdgcn_mfma_f32_16x16x32_bf16(af[rf], bf[cf], acc[rf][cf], 0, 0, 0);
    }

    float* ypk = yp + (size_t)ks * 4096 * 1024;
    #pragma unroll
    for (int rf = 0; rf < 4; rf++) {
        int rowl = wy * 64 + rf * 16 + q4 * 4;
        #pragma unroll
        for (int cf = 0; cf < 4; cf++) {
            int col = d0 + wx * 64 + cf * 16 + l15;
            #pragma unroll
            for (int r = 0; r < 4; r++) {
                int rr = rowl + r;
                if (m0 + rr < cnt) {
                    ypk[(size_t)(off + m0 + rr) * 1024 + col] = acc[rf][cf][r];
                }
            }
        }
    }
}

// ---------------- Kernel 4: gather partials -> out ----------------
// grid NTOK/2, block 256; each half-block does one token row (1024 f32)
__global__ __launch_bounds__(256) void k_gather(
        const float* __restrict__ yp,         // [KSPLIT][4096][1024]
        const int* __restrict__ counts,
        const int* __restrict__ tslot,
        const float* __restrict__ slot_prob,
        float* __restrict__ out) {
    __shared__ int offs[NE];
    int tid = threadIdx.x;
    if (tid < NE) {
        int o = 0;
        for (int i = 0; i < tid; i++) o += counts[i];
        offs[tid] = o;
    }
    __syncthreads();

    int token = blockIdx.x * 2 + (tid >> 7);
    int col = (tid & 127) * 8;

    int s0 = tslot[token * 2], s1 = tslot[token * 2 + 1];
    int g0 = offs[s0 / NTOK] + (s0 % NTOK);
    int g1 = offs[s1 / NTOK] + (s1 % NTOK);
    float pr0 = slot_prob[s0], pr1 = slot_prob[s1];

    const float* p00 = yp + (size_t)g0 * 1024 + col;
    const float* p01 = yp + (size_t)(4096 + g0) * 1024 + col;
    const float* p10 = yp + (size_t)g1 * 1024 + col;
    const float* p11 = yp + (size_t)(4096 + g1) * 1024 + col;
    float* op = out + (size_t)token * 1024 + col;

    #pragma unroll
    for (int v = 0; v < 2; v++) {
        float4 a0 = *(const float4*)(p00 + v * 4);
        float4 a1 = *(const float4*)(p01 + v * 4);
        float4 b0 = *(const float4*)(p10 + v * 4);
        float4 b1 = *(const float4*)(p11 + v * 4);
        float4 r;
        r.x = pr0 * (a0.x + a1.x) + pr1 * (b0.x + b1.x);
        r.y = pr0 * (a0.y + a1.y) + pr1 * (b0.y + b1.y);
        r.z = pr0 * (a0.z + a1.z) + pr1 * (b0.z + b1.z);
        r.w = pr0 * (a0.w + a1.w) + pr1 * (b0.w + b1.w);
        *(float4*)(op + v * 4) = r;
    }
}

// ---------------- launch ----------------
extern "C" void kernel_launch(void* const* d_in, const int* in_sizes, int n_in,
                              void* d_out, int out_size, void* d_ws, size_t ws_size,
                              hipStream_t stream) {
    const float* x      = (const float*)d_in[0];
    const float* g      = (const float*)d_in[1];
    const float* gate_w = (const float*)d_in[2];
    const float* w1     = (const float*)d_in[3];
    const float* w2     = (const float*)d_in[4];
    const float* w3     = (const float*)d_in[5];
    float* out = (float*)d_out;

    char* ws = (char*)d_ws;
    int*   counts     = (int*)ws;                 ws += 256;
    int*   slot_token = (int*)ws;                 ws += NE * NTOK * 4;
    float* slot_prob  = (float*)ws;               ws += NE * NTOK * 4;
    int*   tslot      = (int*)ws;                 ws += NTOK * 2 * 4;
    unsigned short* x_norm = (unsigned short*)ws; ws += (size_t)NTOK * DDIM * 2;           // 4 MB
    unsigned short* hidden = (unsigned short*)ws; ws += (size_t)NTOK * 2 * HDIM * 2;       // 16 MB
    unsigned short* wcatT  = (unsigned short*)ws; ws += (size_t)NE * 4096 * 1024 * 2;      // 64 MB
    unsigned short* w3T    = (unsigned short*)ws; ws += (size_t)NE * 1024 * 2048 * 2;      // 32 MB
    float* yp              = (float*)ws;          ws += (size_t)KSPLIT * 4096 * 1024 * 4;  // 32 MB

    hipMemsetAsync(counts, 0, 256, stream);

    dim3 grid_p(32, 32, 25);
    k_prep<<<grid_p, 256, 0, stream>>>(w1, w2, w3, wcatT, w3T,
                                       x, g, gate_w, x_norm, counts, slot_token, slot_prob, tslot);

    dim3 grid_h(4096 / 128, NTOK / 128, NE);
    k_ffn_h<<<grid_h, 256, 0, stream>>>(x_norm, wcatT, counts, slot_token, hidden);

    dim3 grid_o(1024 / 128, NTOK / 128, NE * KSPLIT);
    k_ffn_out<<<grid_o, 256, 0, stream>>>(hidden, w3T, counts, yp);

    k_gather<<<NTOK / 2, 256, 0, stream>>>(yp, counts, tslot, slot_prob, out);
}